// Round 1
// baseline (513.658 us; speedup 1.0000x reference)
//
#include <hip/hip_runtime.h>

#define N_ROWS 16384
#define N_COLS 4096
#define MARGIN 0.1f
#define BLOCK  256

// One block per row. Each thread loads 4x float4 of cossim and 4x int4 of
// target (coalesced: thread t reads vec index t + k*BLOCK). The thread that
// finds target==1 publishes the correct-class cossim via LDS. Hinge summed
// over ALL columns, then MARGIN subtracted once (correct column contributes
// exactly max(MARGIN,0)=MARGIN).
__global__ __launch_bounds__(BLOCK) void
mm_row_kernel(const float* __restrict__ cossim,
              const int* __restrict__ target,
              float* __restrict__ partials) {
    const int row = blockIdx.x;
    const int t   = threadIdx.x;

    const float4* __restrict__ cos4 = (const float4*)(cossim + (size_t)row * N_COLS);
    const int4*   __restrict__ tgt4 = (const int4*)(target + (size_t)row * N_COLS);

    float4 c[4];
    int4   tg[4];
#pragma unroll
    for (int k = 0; k < 4; ++k) {
        c[k]  = cos4[t + k * BLOCK];
        tg[k] = tgt4[t + k * BLOCK];
    }

    __shared__ float s_cs;
#pragma unroll
    for (int k = 0; k < 4; ++k) {
        if (tg[k].x == 1) s_cs = c[k].x;
        if (tg[k].y == 1) s_cs = c[k].y;
        if (tg[k].z == 1) s_cs = c[k].z;
        if (tg[k].w == 1) s_cs = c[k].w;
    }
    __syncthreads();
    const float cs = s_cs;

    float acc = 0.0f;
#pragma unroll
    for (int k = 0; k < 4; ++k) {
        acc += fmaxf(MARGIN + c[k].x - cs, 0.0f);
        acc += fmaxf(MARGIN + c[k].y - cs, 0.0f);
        acc += fmaxf(MARGIN + c[k].z - cs, 0.0f);
        acc += fmaxf(MARGIN + c[k].w - cs, 0.0f);
    }

    // wave64 shuffle reduce, then cross-wave via LDS
#pragma unroll
    for (int off = 32; off > 0; off >>= 1)
        acc += __shfl_down(acc, off, 64);

    __shared__ float s_wave[BLOCK / 64];
    const int lane = t & 63, wave = t >> 6;
    if (lane == 0) s_wave[wave] = acc;
    __syncthreads();
    if (t == 0) {
        float s = s_wave[0] + s_wave[1] + s_wave[2] + s_wave[3];
        partials[row] = s - MARGIN;  // remove correct-column contribution
    }
}

// Single-block final reduction over 16384 partials; writes d_out[0]
// unconditionally (harness poisons d_out before every timed launch).
__global__ __launch_bounds__(BLOCK) void
mm_reduce_kernel(const float* __restrict__ partials, float* __restrict__ out) {
    const int t = threadIdx.x;
    float acc = 0.0f;
    for (int i = t; i < N_ROWS; i += BLOCK) acc += partials[i];
#pragma unroll
    for (int off = 32; off > 0; off >>= 1)
        acc += __shfl_down(acc, off, 64);
    __shared__ float s_wave[BLOCK / 64];
    const int lane = t & 63, wave = t >> 6;
    if (lane == 0) s_wave[wave] = acc;
    __syncthreads();
    if (t == 0) {
        out[0] = (s_wave[0] + s_wave[1] + s_wave[2] + s_wave[3]) * (1.0f / N_ROWS);
    }
}

extern "C" void kernel_launch(void* const* d_in, const int* in_sizes, int n_in,
                              void* d_out, int out_size, void* d_ws, size_t ws_size,
                              hipStream_t stream) {
    const float* cossim = (const float*)d_in[0];
    const int*   target = (const int*)d_in[1];
    float* out      = (float*)d_out;
    float* partials = (float*)d_ws;  // 16384 floats = 64 KiB, well within ws

    mm_row_kernel<<<N_ROWS, BLOCK, 0, stream>>>(cossim, target, partials);
    mm_reduce_kernel<<<1, BLOCK, 0, stream>>>(partials, out);
}

// Round 2
// 506.561 us; speedup vs baseline: 1.0140x; 1.0140x over previous
//
#include <hip/hip_runtime.h>

#define N_ROWS 16384
#define N_COLS 4096
#define MARGIN 0.1f
#define BLOCK  256
#define RPB    2                      // rows per block
#define NBLOCKS (N_ROWS / RPB)        // 8192

typedef float vf4 __attribute__((ext_vector_type(4)));
typedef int   vi4 __attribute__((ext_vector_type(4)));

// 2 rows per block, 256 threads. Each thread issues 16 independent 16B loads
// (8 cossim float4 + 8 target int4) => 256 B/thread in flight, good MLP.
// The thread that sees target==1 for a row publishes that row's correct-class
// cossim via LDS (one barrier). Hinge is summed over ALL columns of both rows
// (the correct column contributes exactly max(MARGIN,0)=MARGIN each), and
// RPB*MARGIN is subtracted once per block.
__global__ __launch_bounds__(BLOCK) void
mm_row_kernel(const float* __restrict__ cossim,
              const int* __restrict__ target,
              float* __restrict__ partials) {
    const int t = threadIdx.x;
    const size_t r0 = (size_t)blockIdx.x * RPB;

    vf4 c[RPB][4];
    vi4 tg[RPB][4];
#pragma unroll
    for (int r = 0; r < RPB; ++r) {
        const vf4* __restrict__ cos4 = (const vf4*)(cossim + (r0 + r) * N_COLS);
        const vi4* __restrict__ tgt4 = (const vi4*)(target + (r0 + r) * N_COLS);
#pragma unroll
        for (int k = 0; k < 4; ++k) {
            c[r][k]  = cos4[t + k * BLOCK];
            tg[r][k] = tgt4[t + k * BLOCK];
        }
    }

    __shared__ float s_cs[RPB];
#pragma unroll
    for (int r = 0; r < RPB; ++r)
#pragma unroll
        for (int k = 0; k < 4; ++k)
#pragma unroll
            for (int j = 0; j < 4; ++j)
                if (tg[r][k][j] == 1) s_cs[r] = c[r][k][j];
    __syncthreads();

    float acc = 0.0f;
#pragma unroll
    for (int r = 0; r < RPB; ++r) {
        const float mc = MARGIN - s_cs[r];
#pragma unroll
        for (int k = 0; k < 4; ++k)
#pragma unroll
            for (int j = 0; j < 4; ++j)
                acc += fmaxf(mc + c[r][k][j], 0.0f);
    }

    // wave64 shuffle reduce, then cross-wave via LDS
#pragma unroll
    for (int off = 32; off > 0; off >>= 1)
        acc += __shfl_down(acc, off, 64);

    __shared__ float s_wave[BLOCK / 64];
    const int lane = t & 63, wave = t >> 6;
    if (lane == 0) s_wave[wave] = acc;
    __syncthreads();
    if (t == 0) {
        float s = s_wave[0] + s_wave[1] + s_wave[2] + s_wave[3];
        partials[blockIdx.x] = s - (float)RPB * MARGIN;
    }
}

// Single-block final reduction over NBLOCKS partials; writes d_out[0]
// unconditionally (harness poisons d_out before every timed launch).
__global__ __launch_bounds__(BLOCK) void
mm_reduce_kernel(const float* __restrict__ partials, float* __restrict__ out) {
    const int t = threadIdx.x;
    float acc = 0.0f;
    for (int i = t; i < NBLOCKS; i += BLOCK) acc += partials[i];
#pragma unroll
    for (int off = 32; off > 0; off >>= 1)
        acc += __shfl_down(acc, off, 64);
    __shared__ float s_wave[BLOCK / 64];
    const int lane = t & 63, wave = t >> 6;
    if (lane == 0) s_wave[wave] = acc;
    __syncthreads();
    if (t == 0) {
        out[0] = (s_wave[0] + s_wave[1] + s_wave[2] + s_wave[3]) * (1.0f / N_ROWS);
    }
}

extern "C" void kernel_launch(void* const* d_in, const int* in_sizes, int n_in,
                              void* d_out, int out_size, void* d_ws, size_t ws_size,
                              hipStream_t stream) {
    const float* cossim = (const float*)d_in[0];
    const int*   target = (const int*)d_in[1];
    float* out      = (float*)d_out;
    float* partials = (float*)d_ws;  // NBLOCKS floats = 32 KiB

    mm_row_kernel<<<NBLOCKS, BLOCK, 0, stream>>>(cossim, target, partials);
    mm_reduce_kernel<<<1, BLOCK, 0, stream>>>(partials, out);
}

// Round 3
// 502.617 us; speedup vs baseline: 1.0220x; 1.0078x over previous
//
#include <hip/hip_runtime.h>

#define N_ROWS 16384
#define N_COLS 4096
#define MARGIN 0.1f
#define BLOCK  256

typedef float vf4 __attribute__((ext_vector_type(4)));
typedef int   vi4 __attribute__((ext_vector_type(4)));

// Kernel A: pure stream over target (256 MiB). One block per row; thread t
// scans 4 int4 (16 ints). Exactly one element per row is 1: the finder thread
// gathers cossim[row,col] and stores cs_table[row]. No barrier, no reduction.
__global__ __launch_bounds__(BLOCK) void
mm_find_kernel(const int* __restrict__ target,
               const float* __restrict__ cossim,
               float* __restrict__ cs_table) {
    const int row = blockIdx.x;
    const int t   = threadIdx.x;
    const vi4* __restrict__ tgt4 = (const vi4*)(target + (size_t)row * N_COLS);

    vi4 tg[4];
#pragma unroll
    for (int k = 0; k < 4; ++k) tg[k] = tgt4[t + k * BLOCK];

#pragma unroll
    for (int k = 0; k < 4; ++k) {
#pragma unroll
        for (int j = 0; j < 4; ++j) {
            if (tg[k][j] == 1) {
                const int col = (t + k * BLOCK) * 4 + j;
                cs_table[row] = cossim[(size_t)row * N_COLS + col];
            }
        }
    }
}

// Kernel B: pure stream over cossim (256 MiB). One block per row; cs_table is
// 64 KiB (L2-resident). Hinge summed over ALL columns (correct column
// contributes exactly MARGIN; removed once globally in the reduce kernel).
// Only barrier is the cross-wave partial reduce at the end.
__global__ __launch_bounds__(BLOCK) void
mm_hinge_kernel(const float* __restrict__ cossim,
                const float* __restrict__ cs_table,
                float* __restrict__ partials) {
    const int row = blockIdx.x;
    const int t   = threadIdx.x;
    const float mc = MARGIN - cs_table[row];
    const vf4* __restrict__ cos4 = (const vf4*)(cossim + (size_t)row * N_COLS);

    vf4 c[4];
#pragma unroll
    for (int k = 0; k < 4; ++k) c[k] = cos4[t + k * BLOCK];

    float acc = 0.0f;
#pragma unroll
    for (int k = 0; k < 4; ++k)
#pragma unroll
        for (int j = 0; j < 4; ++j)
            acc += fmaxf(mc + c[k][j], 0.0f);

#pragma unroll
    for (int off = 32; off > 0; off >>= 1)
        acc += __shfl_down(acc, off, 64);

    __shared__ float s_wave[BLOCK / 64];
    const int lane = t & 63, wave = t >> 6;
    if (lane == 0) s_wave[wave] = acc;
    __syncthreads();
    if (t == 0)
        partials[row] = s_wave[0] + s_wave[1] + s_wave[2] + s_wave[3];
}

// Final reduction over N_ROWS partials. loss = sum/N - MARGIN (removes the
// correct-column MARGIN contribution of every row in one subtraction).
__global__ __launch_bounds__(BLOCK) void
mm_reduce_kernel(const float* __restrict__ partials, float* __restrict__ out) {
    const int t = threadIdx.x;
    float acc = 0.0f;
    for (int i = t; i < N_ROWS; i += BLOCK) acc += partials[i];
#pragma unroll
    for (int off = 32; off > 0; off >>= 1)
        acc += __shfl_down(acc, off, 64);
    __shared__ float s_wave[BLOCK / 64];
    const int lane = t & 63, wave = t >> 6;
    if (lane == 0) s_wave[wave] = acc;
    __syncthreads();
    if (t == 0)
        out[0] = (s_wave[0] + s_wave[1] + s_wave[2] + s_wave[3]) * (1.0f / N_ROWS)
                 - MARGIN;
}

extern "C" void kernel_launch(void* const* d_in, const int* in_sizes, int n_in,
                              void* d_out, int out_size, void* d_ws, size_t ws_size,
                              hipStream_t stream) {
    const float* cossim = (const float*)d_in[0];
    const int*   target = (const int*)d_in[1];
    float* out      = (float*)d_out;
    float* cs_table = (float*)d_ws;                  // 16384 floats
    float* partials = (float*)d_ws + N_ROWS;         // 16384 floats

    mm_find_kernel<<<N_ROWS, BLOCK, 0, stream>>>(target, cossim, cs_table);
    mm_hinge_kernel<<<N_ROWS, BLOCK, 0, stream>>>(cossim, cs_table, partials);
    mm_reduce_kernel<<<1, BLOCK, 0, stream>>>(partials, out);
}

// Round 4
// 502.237 us; speedup vs baseline: 1.0227x; 1.0008x over previous
//
#include <hip/hip_runtime.h>

#define N_ROWS 16384
#define N_COLS 4096
#define MARGIN 0.1f
#define BLOCK  256
#define NBLK   2048                       // 8 blocks/CU on 256 CUs
#define NV4    (1u << 24)                 // total vec4 elements (2^26 / 4)
#define V4_PER_BLK (NV4 / NBLK)           // 8192 vec4 per block
#define STEPS  (V4_PER_BLK / BLOCK)       // 32 vec4 per thread

typedef float vf4 __attribute__((ext_vector_type(4)));
typedef int   vi4 __attribute__((ext_vector_type(4)));

// Kernel A: flat contiguous stream over target. On a hit (tg==1), the flat
// element index in target equals the flat index in cossim, so the finder
// thread gathers cossim_flat[e] into cs_table[e>>12]. No barrier, no LDS.
__global__ __launch_bounds__(BLOCK) void
mm_find_kernel(const int* __restrict__ target,
               const float* __restrict__ cossim,
               float* __restrict__ cs_table) {
    const vi4* __restrict__ t4 = (const vi4*)target;
    const unsigned base = blockIdx.x * V4_PER_BLK + threadIdx.x;

#pragma unroll
    for (int g = 0; g < STEPS / 4; ++g) {
        vi4 a[4];
        unsigned v[4];
#pragma unroll
        for (int u = 0; u < 4; ++u) {
            v[u] = base + (g * 4 + u) * BLOCK;
            a[u] = t4[v[u]];
        }
#pragma unroll
        for (int u = 0; u < 4; ++u)
#pragma unroll
            for (int j = 0; j < 4; ++j)
                if (a[u][j] == 1) {
                    const size_t e = (size_t)v[u] * 4 + j;
                    cs_table[e >> 12] = cossim[e];
                }
    }
}

// Kernel B: flat contiguous stream over cossim. cs_table[v>>10] is
// wave-uniform per load group (256-aligned chunks never straddle a row's
// 1024-vec4 span) -> broadcast L1/L2 hit. One partial per BLOCK (global sum
// only; per-row sums are never needed). Correct column contributes exactly
// MARGIN per row; subtracted once in the reduce kernel.
__global__ __launch_bounds__(BLOCK) void
mm_hinge_kernel(const float* __restrict__ cossim,
                const float* __restrict__ cs_table,
                float* __restrict__ partials) {
    const vf4* __restrict__ c4 = (const vf4*)cossim;
    const unsigned base = blockIdx.x * V4_PER_BLK + threadIdx.x;

    float acc = 0.0f;
#pragma unroll
    for (int g = 0; g < STEPS / 4; ++g) {
        vf4 a[4];
        float mc[4];
#pragma unroll
        for (int u = 0; u < 4; ++u) {
            const unsigned v = base + (g * 4 + u) * BLOCK;
            a[u]  = c4[v];
            mc[u] = MARGIN - cs_table[v >> 10];
        }
#pragma unroll
        for (int u = 0; u < 4; ++u)
#pragma unroll
            for (int j = 0; j < 4; ++j)
                acc += fmaxf(mc[u] + a[u][j], 0.0f);
    }

#pragma unroll
    for (int off = 32; off > 0; off >>= 1)
        acc += __shfl_down(acc, off, 64);

    __shared__ float s_wave[BLOCK / 64];
    const int lane = threadIdx.x & 63, wave = threadIdx.x >> 6;
    if (lane == 0) s_wave[wave] = acc;
    __syncthreads();
    if (threadIdx.x == 0)
        partials[blockIdx.x] = s_wave[0] + s_wave[1] + s_wave[2] + s_wave[3];
}

// Final reduce over NBLK partials. loss = sum/N - MARGIN.
__global__ __launch_bounds__(BLOCK) void
mm_reduce_kernel(const float* __restrict__ partials, float* __restrict__ out) {
    const int t = threadIdx.x;
    float acc = 0.0f;
    for (int i = t; i < NBLK; i += BLOCK) acc += partials[i];
#pragma unroll
    for (int off = 32; off > 0; off >>= 1)
        acc += __shfl_down(acc, off, 64);
    __shared__ float s_wave[BLOCK / 64];
    const int lane = t & 63, wave = t >> 6;
    if (lane == 0) s_wave[wave] = acc;
    __syncthreads();
    if (t == 0)
        out[0] = (s_wave[0] + s_wave[1] + s_wave[2] + s_wave[3]) * (1.0f / N_ROWS)
                 - MARGIN;
}

extern "C" void kernel_launch(void* const* d_in, const int* in_sizes, int n_in,
                              void* d_out, int out_size, void* d_ws, size_t ws_size,
                              hipStream_t stream) {
    const float* cossim = (const float*)d_in[0];
    const int*   target = (const int*)d_in[1];
    float* out      = (float*)d_out;
    float* cs_table = (float*)d_ws;                  // 16384 floats
    float* partials = (float*)d_ws + N_ROWS;         // NBLK floats

    mm_find_kernel<<<NBLK, BLOCK, 0, stream>>>(target, cossim, cs_table);
    mm_hinge_kernel<<<NBLK, BLOCK, 0, stream>>>(cossim, cs_table, partials);
    mm_reduce_kernel<<<1, BLOCK, 0, stream>>>(partials, out);
}